// Round 1
// baseline (497.098 us; speedup 1.0000x reference)
//
#include <hip/hip_runtime.h>
#include <stdint.h>

typedef unsigned short ushort_t;
typedef __attribute__((ext_vector_type(8))) short short8;
typedef __attribute__((ext_vector_type(8))) unsigned short ushort8;
typedef __attribute__((ext_vector_type(4))) float f32x4;

#define TOK 8192
#define DIM_IN 4096
#define DIM_OUT 4096
#define RANK 64

// fp32 -> bf16 round-to-nearest-even (no NaN inputs in this problem)
__device__ __forceinline__ ushort_t f2bf(float f) {
    unsigned u = __float_as_uint(f);
    unsigned r = (u + 0x7fffu + ((u >> 16) & 1u)) >> 16;
    return (ushort_t)r;
}

__device__ __forceinline__ void gload16(const void* g, void* l) {
    __builtin_amdgcn_global_load_lds(
        (const __attribute__((address_space(1))) unsigned int*)g,
        (__attribute__((address_space(3))) unsigned int*)l,
        16, 0, 0);
}

// ---------------- Kernel 1: input fp32 -> bf16 ----------------
__global__ __launch_bounds__(256) void prep_input_k(const float* __restrict__ in,
                                                    ushort_t* __restrict__ out) {
    size_t idx = (size_t)blockIdx.x * 256 + threadIdx.x;
    const float4* p = (const float4*)(in + idx * 8);
    float4 f0 = p[0], f1 = p[1];
    ushort8 o;
    o[0] = f2bf(f0.x); o[1] = f2bf(f0.y); o[2] = f2bf(f0.z); o[3] = f2bf(f0.w);
    o[4] = f2bf(f1.x); o[5] = f2bf(f1.y); o[6] = f2bf(f1.z); o[7] = f2bf(f1.w);
    *(ushort8*)(out + idx * 8) = o;
}

// ---------------- Kernel 2: W_eff = dequant(Wq,scale) + U*diag(s)*V^T -> bf16 ----------------
// grid 32x32 tiles of 128x128; block 256 threads, each computes 8x8 patch
__global__ __launch_bounds__(256) void prep_weight_k(const float* __restrict__ wq,
                                                     const float* __restrict__ scale,
                                                     const float* __restrict__ U,
                                                     const float* __restrict__ s,
                                                     const float* __restrict__ V,
                                                     ushort_t* __restrict__ Wb) {
    __shared__ float Us[128][64];
    __shared__ float Vs[128][64];
    int tid = threadIdx.x;
    int ob = blockIdx.x >> 5;
    int kb = blockIdx.x & 31;

#pragma unroll
    for (int j = 0; j < 8; ++j) {
        int c = j * 256 + tid;          // float4 slot, 0..2047
        int row = c >> 4;               // 16 float4 per 64-float row
        int col = (c & 15) * 4;
        float4 u = *(const float4*)&U[(size_t)(ob * 128 + row) * RANK + col];
        float4 sv = *(const float4*)&s[col];
        u.x *= sv.x; u.y *= sv.y; u.z *= sv.z; u.w *= sv.w;
        *(float4*)&Us[row][col] = u;
        float4 v = *(const float4*)&V[(size_t)(kb * 128 + row) * RANK + col];
        *(float4*)&Vs[row][col] = v;
    }
    __syncthreads();

    int ty = tid >> 4, tx = tid & 15;
    float acc[8][8];
#pragma unroll
    for (int i = 0; i < 8; ++i)
#pragma unroll
        for (int j = 0; j < 8; ++j) acc[i][j] = 0.f;

#pragma unroll 4
    for (int r4 = 0; r4 < 16; ++r4) {
        float4 u[8], v[8];
#pragma unroll
        for (int i = 0; i < 8; ++i) u[i] = *(const float4*)&Us[ty * 8 + i][r4 * 4];
#pragma unroll
        for (int j = 0; j < 8; ++j) v[j] = *(const float4*)&Vs[tx * 8 + j][r4 * 4];
#pragma unroll
        for (int i = 0; i < 8; ++i)
#pragma unroll
            for (int j = 0; j < 8; ++j)
                acc[i][j] += u[i].x * v[j].x + u[i].y * v[j].y + u[i].z * v[j].z + u[i].w * v[j].w;
    }

#pragma unroll
    for (int i = 0; i < 8; ++i) {
        int o = ob * 128 + ty * 8 + i;
        int k0 = kb * 128 + tx * 8;
        float sc = scale[(size_t)o * (DIM_IN / 32) + (k0 >> 5)];
        float4 q0 = *(const float4*)&wq[(size_t)o * DIM_IN + k0];
        float4 q1 = *(const float4*)&wq[(size_t)o * DIM_IN + k0 + 4];
        ushort8 w;
        w[0] = f2bf(q0.x * sc + acc[i][0]);
        w[1] = f2bf(q0.y * sc + acc[i][1]);
        w[2] = f2bf(q0.z * sc + acc[i][2]);
        w[3] = f2bf(q0.w * sc + acc[i][3]);
        w[4] = f2bf(q1.x * sc + acc[i][4]);
        w[5] = f2bf(q1.y * sc + acc[i][5]);
        w[6] = f2bf(q1.z * sc + acc[i][6]);
        w[7] = f2bf(q1.w * sc + acc[i][7]);
        *(ushort8*)&Wb[(size_t)o * DIM_IN + k0] = w;
    }
}

// ---------------- Kernel 3: C[8192,4096] = A @ B^T + bias (bf16 in, fp32 out) ----------------
// m97 structure: 128x128 tile, BK=32, 4 waves (2x2), 4x4 fragments of mfma_f32_16x16x32_bf16,
// double-buffered LDS, global_load_lds width 16, XCD-aware block swizzle.
__global__ __launch_bounds__(256) void gemm_k(const ushort_t* __restrict__ A,
                                              const ushort_t* __restrict__ B,
                                              const float* __restrict__ bias,
                                              float* __restrict__ C) {
    __shared__ ushort_t As[2][128 * 32];
    __shared__ ushort_t Bs[2][128 * 32];

    int tid = threadIdx.x;
    int wave = tid >> 6, lane = tid & 63;
    int bid = blockIdx.x;
    // XCD swizzle: 2048 blocks, 8 XCDs, 256 contiguous tiles per XCD
    int swz = (bid & 7) * 256 + (bid >> 3);
    int bm = swz >> 5;   // 64 M-tiles
    int bn = swz & 31;   // 32 N-tiles

    int wr = wave >> 1, wc = wave & 1;
    int lrow = lane & 15;
    int lk = (lane >> 4) * 8;

    f32x4 acc[4][4] = {};

    auto stage = [&](int buf, int kt) {
#pragma unroll
        for (int r = 0; r < 2; ++r) {
            int c = r * 256 + tid;                 // 16B chunk id (0..511)
            int row = c >> 2;
            int col = (c & 3) * 8;
            gload16(A + (size_t)(bm * 128 + row) * DIM_IN + kt + col,
                    &As[buf][(r * 256 + wave * 64) * 8]);
            gload16(B + (size_t)(bn * 128 + row) * DIM_IN + kt + col,
                    &Bs[buf][(r * 256 + wave * 64) * 8]);
        }
    };

    auto compute = [&](int buf) {
        short8 a[4], b[4];
#pragma unroll
        for (int m = 0; m < 4; ++m)
            a[m] = *(const short8*)&As[buf][(wr * 64 + m * 16 + lrow) * 32 + lk];
#pragma unroll
        for (int n = 0; n < 4; ++n)
            b[n] = *(const short8*)&Bs[buf][(wc * 64 + n * 16 + lrow) * 32 + lk];
#pragma unroll
        for (int m = 0; m < 4; ++m)
#pragma unroll
            for (int n = 0; n < 4; ++n)
                acc[m][n] = __builtin_amdgcn_mfma_f32_16x16x32_bf16(a[m], b[n], acc[m][n], 0, 0, 0);
    };

    stage(0, 0);
    __syncthreads();
    int cur = 0;
    for (int kt = 32; kt < DIM_IN; kt += 32) {
        stage(cur ^ 1, kt);
        compute(cur);
        __syncthreads();
        cur ^= 1;
    }
    compute(cur);

    // epilogue: C/D layout col=lane&15, row=(lane>>4)*4+reg
    int ccol = lane & 15;
    int crow = (lane >> 4) * 4;
#pragma unroll
    for (int n = 0; n < 4; ++n) {
        int gcol = bn * 128 + wc * 64 + n * 16 + ccol;
        float bv = bias[gcol];
#pragma unroll
        for (int m = 0; m < 4; ++m) {
            size_t grow = (size_t)(bm * 128 + wr * 64 + m * 16 + crow);
#pragma unroll
            for (int r = 0; r < 4; ++r)
                C[(grow + r) * DIM_OUT + gcol] = acc[m][n][r] + bv;
        }
    }
}

extern "C" void kernel_launch(void* const* d_in, const int* in_sizes, int n_in,
                              void* d_out, int out_size, void* d_ws, size_t ws_size,
                              hipStream_t stream) {
    const float* input = (const float*)d_in[0];
    const float* wq    = (const float*)d_in[1];
    const float* scale = (const float*)d_in[2];
    const float* bias  = (const float*)d_in[3];
    const float* U     = (const float*)d_in[4];
    const float* s     = (const float*)d_in[5];
    const float* V     = (const float*)d_in[6];
    float* out = (float*)d_out;

    ushort_t* Abf = (ushort_t*)d_ws;                       // 8192*4096*2 = 64 MB
    ushort_t* Wbf = Abf + (size_t)TOK * DIM_IN;            // 4096*4096*2 = 32 MB

    prep_input_k<<<(TOK * DIM_IN) / (256 * 8), 256, 0, stream>>>(input, Abf);
    prep_weight_k<<<(DIM_OUT / 128) * (DIM_IN / 128), 256, 0, stream>>>(wq, scale, U, s, V, Wbf);
    gemm_k<<<(TOK / 128) * (DIM_OUT / 128), 256, 0, stream>>>(Abf, Wbf, bias, out);
}

// Round 2
// 340.105 us; speedup vs baseline: 1.4616x; 1.4616x over previous
//
#include <hip/hip_runtime.h>
#include <stdint.h>

typedef unsigned short ushort_t;
typedef __attribute__((ext_vector_type(8))) short short8;
typedef __attribute__((ext_vector_type(8))) unsigned short ushort8;
typedef __attribute__((ext_vector_type(4))) float f32x4;

#define TOK 8192
#define DIM_IN 4096
#define DIM_OUT 4096
#define RANK 64
#define NT (DIM_IN / 64)   // 64 K-tiles of BK=64

// fp32 -> bf16 round-to-nearest-even
__device__ __forceinline__ ushort_t f2bf(float f) {
    unsigned u = __float_as_uint(f);
    unsigned r = (u + 0x7fffu + ((u >> 16) & 1u)) >> 16;
    return (ushort_t)r;
}

__device__ __forceinline__ void gload16(const void* g, void* l) {
    __builtin_amdgcn_global_load_lds(
        (const __attribute__((address_space(1))) unsigned int*)g,
        (__attribute__((address_space(3))) unsigned int*)l,
        16, 0, 0);
}

// ---------------- Kernel 1: input fp32 -> bf16 ----------------
__global__ __launch_bounds__(256) void prep_input_k(const float* __restrict__ in,
                                                    ushort_t* __restrict__ out) {
    size_t idx = (size_t)blockIdx.x * 256 + threadIdx.x;
    const float4* p = (const float4*)(in + idx * 8);
    float4 f0 = p[0], f1 = p[1];
    ushort8 o;
    o[0] = f2bf(f0.x); o[1] = f2bf(f0.y); o[2] = f2bf(f0.z); o[3] = f2bf(f0.w);
    o[4] = f2bf(f1.x); o[5] = f2bf(f1.y); o[6] = f2bf(f1.z); o[7] = f2bf(f1.w);
    *(ushort8*)(out + idx * 8) = o;
}

// ---------------- Kernel 2: W_eff = dequant(Wq,scale) + U*diag(s)*V^T -> bf16 ----------------
__global__ __launch_bounds__(256) void prep_weight_k(const float* __restrict__ wq,
                                                     const float* __restrict__ scale,
                                                     const float* __restrict__ U,
                                                     const float* __restrict__ s,
                                                     const float* __restrict__ V,
                                                     ushort_t* __restrict__ Wb) {
    __shared__ float Us[128][64];
    __shared__ float Vs[128][64];
    int tid = threadIdx.x;
    int ob = blockIdx.x >> 5;
    int kb = blockIdx.x & 31;

#pragma unroll
    for (int j = 0; j < 8; ++j) {
        int c = j * 256 + tid;
        int row = c >> 4;
        int col = (c & 15) * 4;
        float4 u = *(const float4*)&U[(size_t)(ob * 128 + row) * RANK + col];
        float4 sv = *(const float4*)&s[col];
        u.x *= sv.x; u.y *= sv.y; u.z *= sv.z; u.w *= sv.w;
        *(float4*)&Us[row][col] = u;
        float4 v = *(const float4*)&V[(size_t)(kb * 128 + row) * RANK + col];
        *(float4*)&Vs[row][col] = v;
    }
    __syncthreads();

    int ty = tid >> 4, tx = tid & 15;
    float acc[8][8];
#pragma unroll
    for (int i = 0; i < 8; ++i)
#pragma unroll
        for (int j = 0; j < 8; ++j) acc[i][j] = 0.f;

#pragma unroll 4
    for (int r4 = 0; r4 < 16; ++r4) {
        float4 u[8], v[8];
#pragma unroll
        for (int i = 0; i < 8; ++i) u[i] = *(const float4*)&Us[ty * 8 + i][r4 * 4];
#pragma unroll
        for (int j = 0; j < 8; ++j) v[j] = *(const float4*)&Vs[tx * 8 + j][r4 * 4];
#pragma unroll
        for (int i = 0; i < 8; ++i)
#pragma unroll
            for (int j = 0; j < 8; ++j)
                acc[i][j] += u[i].x * v[j].x + u[i].y * v[j].y + u[i].z * v[j].z + u[i].w * v[j].w;
    }

#pragma unroll
    for (int i = 0; i < 8; ++i) {
        int o = ob * 128 + ty * 8 + i;
        int k0 = kb * 128 + tx * 8;
        float sc = scale[(size_t)o * (DIM_IN / 32) + (k0 >> 5)];
        float4 q0 = *(const float4*)&wq[(size_t)o * DIM_IN + k0];
        float4 q1 = *(const float4*)&wq[(size_t)o * DIM_IN + k0 + 4];
        ushort8 w;
        w[0] = f2bf(q0.x * sc + acc[i][0]);
        w[1] = f2bf(q0.y * sc + acc[i][1]);
        w[2] = f2bf(q0.z * sc + acc[i][2]);
        w[3] = f2bf(q0.w * sc + acc[i][3]);
        w[4] = f2bf(q1.x * sc + acc[i][4]);
        w[5] = f2bf(q1.y * sc + acc[i][5]);
        w[6] = f2bf(q1.z * sc + acc[i][6]);
        w[7] = f2bf(q1.w * sc + acc[i][7]);
        *(ushort8*)&Wb[(size_t)o * DIM_IN + k0] = w;
    }
}

// ---------------- Kernel 3: 256^2 8-phase GEMM, C = A @ B^T + bias ----------------
// 512 threads (8 waves, 2M x 4N), BK=64, st_16x32-swizzled LDS, counted vmcnt(6),
// setprio around MFMA clusters. LDS 128 KiB: [buf][A/B][half][128x64 bf16 subtiled].
__global__ __launch_bounds__(512, 2) void gemm_k(const ushort_t* __restrict__ A,
                                                 const ushort_t* __restrict__ B,
                                                 const float* __restrict__ bias,
                                                 float* __restrict__ C) {
    __shared__ ushort_t lds[2][2][2][8192];

    const int tid = threadIdx.x;
    const int wid = tid >> 6;
    const int lane = tid & 63;

    // XCD-aware bijective swizzle: 512 blocks, 8 XCDs, 64 per XCD
    int bid = blockIdx.x;
    int swz = (bid & 7) * 64 + (bid >> 3);
    const int bm = swz >> 4;   // 32 M-tiles
    const int bn = swz & 15;   // 16 N-tiles

    const int wr = wid >> 2;   // 0..1 (M)
    const int wc = wid & 3;    // 0..3 (N)

    // --- staging: wave wid fills subtiles {wid, wid+8} of each 128x64 half-tile.
    // LDS linear dest (lane*16B); global src pre-swizzled (inverse of st_16x32).
    const int lane2 = lane ^ (((lane >> 5) & 1) << 1);
    const int srow = (wid >> 1) * 16 + (lane2 >> 2);
    const int scol = (wid & 1) * 32 + (lane2 & 3) * 8;
    const ushort_t* pa = A + (size_t)(bm * 256 + srow) * DIM_IN + scol;
    const ushort_t* pb = B + (size_t)(bn * 256 + srow) * DIM_IN + scol;

    // --- swizzled per-lane ds_read offset (element units) for 16x16x32 fragments
    const int loff = ((((lane & 15) * 64 + (lane >> 4) * 16) ^ (((lane >> 3) & 1) << 5)) >> 1);

    f32x4 acc[8][4] = {};

    auto stageA = [&](int buf, int half, int t) {
        const ushort_t* g = pa + (size_t)half * 128 * DIM_IN + t * 64;
        gload16(g, &lds[buf][0][half][wid * 512]);
        gload16(g + (size_t)64 * DIM_IN, &lds[buf][0][half][(wid + 8) * 512]);
    };
    auto stageB = [&](int buf, int half, int t) {
        const ushort_t* g = pb + (size_t)half * 128 * DIM_IN + t * 64;
        gload16(g, &lds[buf][1][half][wid * 512]);
        gload16(g + (size_t)64 * DIM_IN, &lds[buf][1][half][(wid + 8) * 512]);
    };

    // mode: 2 = steady state (full staging, vmcnt(6)); 1 = t=NT-2 (only P0 stage, vmcnt(0));
    //       0 = last tile (no staging, no trailing wait/barrier)
    auto tile_step = [&](int buf, int t, int mode) {
        const ushort_t* LA = &lds[buf][0][wr][0];
        const ushort_t* LB = &lds[buf][1][wc >> 1][0];
        const int bsub = (wc & 1) * 4;
        short8 a[4][2], b[4][2];

        // ---- P0: read A m0-3 + B n0-1; stage A1(t+1) -> buf^1
#pragma unroll
        for (int m = 0; m < 4; ++m)
#pragma unroll
            for (int kk = 0; kk < 2; ++kk)
                a[m][kk] = *(const short8*)(LA + ((m * 2 + kk) << 9) + loff);
#pragma unroll
        for (int n = 0; n < 2; ++n)
#pragma unroll
            for (int kk = 0; kk < 2; ++kk)
                b[n][kk] = *(const short8*)(LB + (((bsub + n) * 2 + kk) << 9) + loff);
        if (mode >= 1) stageA(buf ^ 1, 1, t + 1);
        asm volatile("s_waitcnt lgkmcnt(8)" ::: "memory");
        __builtin_amdgcn_s_barrier();
        asm volatile("s_waitcnt lgkmcnt(0)" ::: "memory");
        __builtin_amdgcn_s_setprio(1);
#pragma unroll
        for (int m = 0; m < 4; ++m)
#pragma unroll
            for (int n = 0; n < 2; ++n)
#pragma unroll
                for (int kk = 0; kk < 2; ++kk)
                    acc[m][n] = __builtin_amdgcn_mfma_f32_16x16x32_bf16(a[m][kk], b[n][kk], acc[m][n], 0, 0, 0);
        __builtin_amdgcn_s_setprio(0);
        __builtin_amdgcn_s_barrier();

        // ---- P1: read B n2-3; MFMA m0-3 x n2-3 (A region reads not done yet)
#pragma unroll
        for (int n = 0; n < 2; ++n)
#pragma unroll
            for (int kk = 0; kk < 2; ++kk)
                b[2 + n][kk] = *(const short8*)(LB + (((bsub + 2 + n) * 2 + kk) << 9) + loff);
        __builtin_amdgcn_s_barrier();
        asm volatile("s_waitcnt lgkmcnt(0)" ::: "memory");
        __builtin_amdgcn_s_setprio(1);
#pragma unroll
        for (int m = 0; m < 4; ++m)
#pragma unroll
            for (int n = 0; n < 2; ++n)
#pragma unroll
                for (int kk = 0; kk < 2; ++kk)
                    acc[m][2 + n] = __builtin_amdgcn_mfma_f32_16x16x32_bf16(a[m][kk], b[2 + n][kk], acc[m][2 + n], 0, 0, 0);
        __builtin_amdgcn_s_setprio(0);
        __builtin_amdgcn_s_barrier();
        // B region of buf free chip-wide from here (all B reads drained before that barrier)

        // ---- P2: read A m4-7; stage B0(t+2) -> buf (B region free)
#pragma unroll
        for (int m = 0; m < 4; ++m)
#pragma unroll
            for (int kk = 0; kk < 2; ++kk)
                a[m][kk] = *(const short8*)(LA + (((m + 4) * 2 + kk) << 9) + loff);
        if (mode == 2) stageB(buf, 0, t + 2);
        __builtin_amdgcn_s_barrier();
        asm volatile("s_waitcnt lgkmcnt(0)" ::: "memory");
        __builtin_amdgcn_s_setprio(1);
#pragma unroll
        for (int m = 0; m < 4; ++m)
#pragma unroll
            for (int n = 0; n < 2; ++n)
#pragma unroll
                for (int kk = 0; kk < 2; ++kk)
                    acc[4 + m][n] = __builtin_amdgcn_mfma_f32_16x16x32_bf16(a[m][kk], b[n][kk], acc[4 + m][n], 0, 0, 0);
        __builtin_amdgcn_s_setprio(0);
        __builtin_amdgcn_s_barrier();
        // A region of buf free chip-wide from here

        // ---- P3: stage B1(t+2) + A0(t+2) -> buf; MFMA m4-7 x n2-3; vmcnt; barrier
        if (mode == 2) { stageB(buf, 1, t + 2); stageA(buf, 0, t + 2); }
        __builtin_amdgcn_s_barrier();
        __builtin_amdgcn_s_setprio(1);
#pragma unroll
        for (int m = 0; m < 4; ++m)
#pragma unroll
            for (int n = 0; n < 2; ++n)
#pragma unroll
                for (int kk = 0; kk < 2; ++kk)
                    acc[4 + m][2 + n] = __builtin_amdgcn_mfma_f32_16x16x32_bf16(a[m][kk], b[2 + n][kk], acc[4 + m][2 + n], 0, 0, 0);
        __builtin_amdgcn_s_setprio(0);
        if (mode == 2)
            asm volatile("s_waitcnt vmcnt(6)" ::: "memory");   // 3 half-tiles in flight
        else if (mode == 1)
            asm volatile("s_waitcnt vmcnt(0)" ::: "memory");   // tail drain
        if (mode >= 1) __builtin_amdgcn_s_barrier();
    };

    // ---- prologue: tile0 (4 halves) + tile1 (B0,B1,A0); A1(t1) comes at t0.P0
    stageA(0, 0, 0); stageA(0, 1, 0); stageB(0, 0, 0); stageB(0, 1, 0);
    stageB(1, 0, 1); stageB(1, 1, 1); stageA(1, 0, 1);
    asm volatile("s_waitcnt vmcnt(6)" ::: "memory");           // tile0 landed, 3 halves in flight
    __builtin_amdgcn_s_barrier();

    for (int t = 0; t < NT - 2; t += 2) {
        tile_step(0, t, 2);
        tile_step(1, t + 1, 2);
    }
    tile_step(0, NT - 2, 1);
    tile_step(1, NT - 1, 0);

    // ---- epilogue: C/D layout col = lane&15, row = (lane>>4)*4 + reg
    const int ccol = lane & 15;
    const int crow = (lane >> 4) * 4;
#pragma unroll
    for (int n = 0; n < 4; ++n) {
        int gcol = bn * 256 + wc * 64 + n * 16 + ccol;
        float bv = bias[gcol];
#pragma unroll
        for (int m = 0; m < 8; ++m) {
            size_t grow = (size_t)(bm * 256 + wr * 128 + m * 16 + crow);
#pragma unroll
            for (int r = 0; r < 4; ++r)
                C[(grow + r) * DIM_OUT + gcol] = acc[m][n][r] + bv;
        }
    }
}

extern "C" void kernel_launch(void* const* d_in, const int* in_sizes, int n_in,
                              void* d_out, int out_size, void* d_ws, size_t ws_size,
                              hipStream_t stream) {
    const float* input = (const float*)d_in[0];
    const float* wq    = (const float*)d_in[1];
    const float* scale = (const float*)d_in[2];
    const float* bias  = (const float*)d_in[3];
    const float* U     = (const float*)d_in[4];
    const float* s     = (const float*)d_in[5];
    const float* V     = (const float*)d_in[6];
    float* out = (float*)d_out;

    ushort_t* Abf = (ushort_t*)d_ws;                       // 8192*4096*2 = 64 MB
    ushort_t* Wbf = Abf + (size_t)TOK * DIM_IN;            // 4096*4096*2 = 32 MB

    prep_input_k<<<(TOK * DIM_IN) / (256 * 8), 256, 0, stream>>>(input, Abf);
    prep_weight_k<<<(DIM_OUT / 128) * (DIM_IN / 128), 256, 0, stream>>>(wq, scale, U, s, V, Wbf);
    gemm_k<<<(TOK / 256) * (DIM_OUT / 256), 512, 0, stream>>>(Abf, Wbf, bias, out);
}

// Round 3
// 338.623 us; speedup vs baseline: 1.4680x; 1.0044x over previous
//
#include <hip/hip_runtime.h>
#include <stdint.h>

typedef unsigned short ushort_t;
typedef __attribute__((ext_vector_type(8))) short short8;
typedef __attribute__((ext_vector_type(8))) unsigned short ushort8;
typedef __attribute__((ext_vector_type(4))) float f32x4;

#define TOK 8192
#define DIM_IN 4096
#define DIM_OUT 4096
#define RANK 64
#define NT (DIM_IN / 64)   // 64 K-tiles of BK=64

// fp32 -> bf16 round-to-nearest-even
__device__ __forceinline__ ushort_t f2bf(float f) {
    unsigned u = __float_as_uint(f);
    unsigned r = (u + 0x7fffu + ((u >> 16) & 1u)) >> 16;
    return (ushort_t)r;
}

__device__ __forceinline__ void gload16(const void* g, void* l) {
    __builtin_amdgcn_global_load_lds(
        (const __attribute__((address_space(1))) unsigned int*)g,
        (__attribute__((address_space(3))) unsigned int*)l,
        16, 0, 0);
}

// ---------------- Kernel 1: input fp32 -> bf16 ----------------
__global__ __launch_bounds__(256) void prep_input_k(const float* __restrict__ in,
                                                    ushort_t* __restrict__ out) {
    size_t idx = (size_t)blockIdx.x * 256 + threadIdx.x;
    const float4* p = (const float4*)(in + idx * 8);
    float4 f0 = p[0], f1 = p[1];
    ushort8 o;
    o[0] = f2bf(f0.x); o[1] = f2bf(f0.y); o[2] = f2bf(f0.z); o[3] = f2bf(f0.w);
    o[4] = f2bf(f1.x); o[5] = f2bf(f1.y); o[6] = f2bf(f1.z); o[7] = f2bf(f1.w);
    *(ushort8*)(out + idx * 8) = o;
}

// ---------------- Kernel 2: W_eff = dequant(Wq,scale) + U*diag(s)*V^T -> bf16 ----------------
__global__ __launch_bounds__(256) void prep_weight_k(const float* __restrict__ wq,
                                                     const float* __restrict__ scale,
                                                     const float* __restrict__ U,
                                                     const float* __restrict__ s,
                                                     const float* __restrict__ V,
                                                     ushort_t* __restrict__ Wb) {
    __shared__ float Us[128][64];
    __shared__ float Vs[128][64];
    int tid = threadIdx.x;
    int ob = blockIdx.x >> 5;
    int kb = blockIdx.x & 31;

#pragma unroll
    for (int j = 0; j < 8; ++j) {
        int c = j * 256 + tid;
        int row = c >> 4;
        int col = (c & 15) * 4;
        float4 u = *(const float4*)&U[(size_t)(ob * 128 + row) * RANK + col];
        float4 sv = *(const float4*)&s[col];
        u.x *= sv.x; u.y *= sv.y; u.z *= sv.z; u.w *= sv.w;
        *(float4*)&Us[row][col] = u;
        float4 v = *(const float4*)&V[(size_t)(kb * 128 + row) * RANK + col];
        *(float4*)&Vs[row][col] = v;
    }
    __syncthreads();

    int ty = tid >> 4, tx = tid & 15;
    float acc[8][8];
#pragma unroll
    for (int i = 0; i < 8; ++i)
#pragma unroll
        for (int j = 0; j < 8; ++j) acc[i][j] = 0.f;

#pragma unroll 4
    for (int r4 = 0; r4 < 16; ++r4) {
        float4 u[8], v[8];
#pragma unroll
        for (int i = 0; i < 8; ++i) u[i] = *(const float4*)&Us[ty * 8 + i][r4 * 4];
#pragma unroll
        for (int j = 0; j < 8; ++j) v[j] = *(const float4*)&Vs[tx * 8 + j][r4 * 4];
#pragma unroll
        for (int i = 0; i < 8; ++i)
#pragma unroll
            for (int j = 0; j < 8; ++j)
                acc[i][j] += u[i].x * v[j].x + u[i].y * v[j].y + u[i].z * v[j].z + u[i].w * v[j].w;
    }

#pragma unroll
    for (int i = 0; i < 8; ++i) {
        int o = ob * 128 + ty * 8 + i;
        int k0 = kb * 128 + tx * 8;
        float sc = scale[(size_t)o * (DIM_IN / 32) + (k0 >> 5)];
        float4 q0 = *(const float4*)&wq[(size_t)o * DIM_IN + k0];
        float4 q1 = *(const float4*)&wq[(size_t)o * DIM_IN + k0 + 4];
        ushort8 w;
        w[0] = f2bf(q0.x * sc + acc[i][0]);
        w[1] = f2bf(q0.y * sc + acc[i][1]);
        w[2] = f2bf(q0.z * sc + acc[i][2]);
        w[3] = f2bf(q0.w * sc + acc[i][3]);
        w[4] = f2bf(q1.x * sc + acc[i][4]);
        w[5] = f2bf(q1.y * sc + acc[i][5]);
        w[6] = f2bf(q1.z * sc + acc[i][6]);
        w[7] = f2bf(q1.w * sc + acc[i][7]);
        *(ushort8*)&Wb[(size_t)o * DIM_IN + k0] = w;
    }
}

// ---------------- Kernel 3: 256^2 8-phase GEMM, C = A @ B^T + bias ----------------
// 512 threads (8 waves, 2M x 4N), BK=64, st_16x32-swizzled LDS, counted vmcnt(6),
// setprio around MFMA clusters. Read-ahead: each phase's ds_reads are issued one
// phase early (b23 before Q0's MFMAs; a47 after Q1's, where a03's registers die),
// so every lgkm wait except P0's is covered by an MFMA cluster or barrier sync.
__global__ __launch_bounds__(512, 2) void gemm_k(const ushort_t* __restrict__ A,
                                                 const ushort_t* __restrict__ B,
                                                 const float* __restrict__ bias,
                                                 float* __restrict__ C) {
    __shared__ ushort_t lds[2][2][2][8192];

    const int tid = threadIdx.x;
    const int wid = tid >> 6;
    const int lane = tid & 63;

    // XCD-aware bijective swizzle: 512 blocks, 8 XCDs, 64 per XCD
    int bid = blockIdx.x;
    int swz = (bid & 7) * 64 + (bid >> 3);
    const int bm = swz >> 4;   // 32 M-tiles
    const int bn = swz & 15;   // 16 N-tiles

    const int wr = wid >> 2;   // 0..1 (M)
    const int wc = wid & 3;    // 0..3 (N)

    // --- staging: wave wid fills subtiles {wid, wid+8} of each 128x64 half-tile.
    const int lane2 = lane ^ (((lane >> 5) & 1) << 1);
    const int srow = (wid >> 1) * 16 + (lane2 >> 2);
    const int scol = (wid & 1) * 32 + (lane2 & 3) * 8;
    const ushort_t* pa = A + (size_t)(bm * 256 + srow) * DIM_IN + scol;
    const ushort_t* pb = B + (size_t)(bn * 256 + srow) * DIM_IN + scol;

    // --- swizzled per-lane ds_read offset (element units)
    const int loff = ((((lane & 15) * 64 + (lane >> 4) * 16) ^ (((lane >> 3) & 1) << 5)) >> 1);

    f32x4 acc[8][4] = {};

    auto stageA = [&](int buf, int half, int t) {
        const ushort_t* g = pa + (size_t)half * 128 * DIM_IN + t * 64;
        gload16(g, &lds[buf][0][half][wid * 512]);
        gload16(g + (size_t)64 * DIM_IN, &lds[buf][0][half][(wid + 8) * 512]);
    };
    auto stageB = [&](int buf, int half, int t) {
        const ushort_t* g = pb + (size_t)half * 128 * DIM_IN + t * 64;
        gload16(g, &lds[buf][1][half][wid * 512]);
        gload16(g + (size_t)64 * DIM_IN, &lds[buf][1][half][(wid + 8) * 512]);
    };

    // mode: 2 = steady state; 1 = t=NT-2 (only P0 stage, vmcnt(0)); 0 = last tile
    auto tile_step = [&](int buf, int t, int mode) {
        const ushort_t* LA = &lds[buf][0][wr][0];
        const ushort_t* LB = &lds[buf][1][wc >> 1][0];
        const int bsub = (wc & 1) * 4;
        short8 a[4][2], b[4][2];

        // ---- P0: issue a03(8)+b01(4)+b23(4, read-ahead); stage A1(t+1)
#pragma unroll
        for (int m = 0; m < 4; ++m)
#pragma unroll
            for (int kk = 0; kk < 2; ++kk)
                a[m][kk] = *(const short8*)(LA + ((m * 2 + kk) << 9) + loff);
#pragma unroll
        for (int n = 0; n < 4; ++n)
#pragma unroll
            for (int kk = 0; kk < 2; ++kk)
                b[n][kk] = *(const short8*)(LB + (((bsub + n) * 2 + kk) << 9) + loff);
        if (mode >= 1) stageA(buf ^ 1, 1, t + 1);
        asm volatile("s_waitcnt lgkmcnt(8)" ::: "memory");
        __builtin_amdgcn_s_barrier();
        asm volatile("s_waitcnt lgkmcnt(4)" ::: "memory");  // a03,b01 ready; b23 in flight
        __builtin_amdgcn_s_setprio(1);
#pragma unroll
        for (int kk = 0; kk < 2; ++kk)
#pragma unroll
            for (int m = 0; m < 4; ++m)
#pragma unroll
                for (int n = 0; n < 2; ++n)
                    acc[m][n] = __builtin_amdgcn_mfma_f32_16x16x32_bf16(a[m][kk], b[n][kk], acc[m][n], 0, 0, 0);
        __builtin_amdgcn_s_setprio(0);
        __builtin_amdgcn_s_barrier();

        // ---- P1: MFMA m03 x n23 (b23 latency hidden under Q0); then issue a47
        //      (a03's registers die here -> reuse, no VGPR growth)
        asm volatile("s_waitcnt lgkmcnt(0)" ::: "memory");
        __builtin_amdgcn_s_setprio(1);
#pragma unroll
        for (int kk = 0; kk < 2; ++kk)
#pragma unroll
            for (int m = 0; m < 4; ++m)
#pragma unroll
                for (int n = 0; n < 2; ++n)
                    acc[m][2 + n] = __builtin_amdgcn_mfma_f32_16x16x32_bf16(a[m][kk], b[2 + n][kk], acc[m][2 + n], 0, 0, 0);
        __builtin_amdgcn_s_setprio(0);
#pragma unroll
        for (int m = 0; m < 4; ++m)
#pragma unroll
            for (int kk = 0; kk < 2; ++kk)
                a[m][kk] = *(const short8*)(LA + (((m + 4) * 2 + kk) << 9) + loff);
        __builtin_amdgcn_s_barrier();
        // all waves' B reads of tile t complete chip-wide from here

        // ---- P2: stage B0,B1(t+2); MFMA m47 x n01 (a47 covered by barrier+stage)
        if (mode == 2) { stageB(buf, 0, t + 2); stageB(buf, 1, t + 2); }
        __builtin_amdgcn_s_barrier();
        asm volatile("s_waitcnt lgkmcnt(0)" ::: "memory");
        __builtin_amdgcn_s_setprio(1);
#pragma unroll
        for (int kk = 0; kk < 2; ++kk)
#pragma unroll
            for (int m = 0; m < 4; ++m)
#pragma unroll
                for (int n = 0; n < 2; ++n)
                    acc[4 + m][n] = __builtin_amdgcn_mfma_f32_16x16x32_bf16(a[m][kk], b[n][kk], acc[4 + m][n], 0, 0, 0);
        __builtin_amdgcn_s_setprio(0);
        __builtin_amdgcn_s_barrier();
        // all waves' A reads of tile t complete chip-wide from here

        // ---- P3: stage A0(t+2); MFMA m47 x n23 (operands already waited); vmcnt
        if (mode == 2) stageA(buf, 0, t + 2);
        __builtin_amdgcn_s_barrier();
        __builtin_amdgcn_s_setprio(1);
#pragma unroll
        for (int kk = 0; kk < 2; ++kk)
#pragma unroll
            for (int m = 0; m < 4; ++m)
#pragma unroll
                for (int n = 0; n < 2; ++n)
                    acc[4 + m][2 + n] = __builtin_amdgcn_mfma_f32_16x16x32_bf16(a[m][kk], b[2 + n][kk], acc[4 + m][2 + n], 0, 0, 0);
        __builtin_amdgcn_s_setprio(0);
        if (mode == 2)
            asm volatile("s_waitcnt vmcnt(6)" ::: "memory");   // 3 half-tiles in flight
        else if (mode == 1)
            asm volatile("s_waitcnt vmcnt(0)" ::: "memory");   // tail drain
        if (mode >= 1) __builtin_amdgcn_s_barrier();
    };

    // ---- prologue: tile0 (4 halves) + tile1 (B0,B1,A0); A1(t1) comes at t0.P0
    stageA(0, 0, 0); stageA(0, 1, 0); stageB(0, 0, 0); stageB(0, 1, 0);
    stageB(1, 0, 1); stageB(1, 1, 1); stageA(1, 0, 1);
    asm volatile("s_waitcnt vmcnt(6)" ::: "memory");           // tile0 landed
    __builtin_amdgcn_s_barrier();

    for (int t = 0; t < NT - 2; t += 2) {
        tile_step(0, t, 2);
        tile_step(1, t + 1, 2);
    }
    tile_step(0, NT - 2, 1);
    tile_step(1, NT - 1, 0);

    // ---- epilogue: C/D layout col = lane&15, row = (lane>>4)*4 + reg
    const int ccol = lane & 15;
    const int crow = (lane >> 4) * 4;
#pragma unroll
    for (int n = 0; n < 4; ++n) {
        int gcol = bn * 256 + wc * 64 + n * 16 + ccol;
        float bv = bias[gcol];
#pragma unroll
        for (int m = 0; m < 8; ++m) {
            size_t grow = (size_t)(bm * 256 + wr * 128 + m * 16 + crow);
#pragma unroll
            for (int r = 0; r < 4; ++r)
                C[(grow + r) * DIM_OUT + gcol] = acc[m][n][r] + bv;
        }
    }
}

extern "C" void kernel_launch(void* const* d_in, const int* in_sizes, int n_in,
                              void* d_out, int out_size, void* d_ws, size_t ws_size,
                              hipStream_t stream) {
    const float* input = (const float*)d_in[0];
    const float* wq    = (const float*)d_in[1];
    const float* scale = (const float*)d_in[2];
    const float* bias  = (const float*)d_in[3];
    const float* U     = (const float*)d_in[4];
    const float* s     = (const float*)d_in[5];
    const float* V     = (const float*)d_in[6];
    float* out = (float*)d_out;

    ushort_t* Abf = (ushort_t*)d_ws;                       // 8192*4096*2 = 64 MB
    ushort_t* Wbf = Abf + (size_t)TOK * DIM_IN;            // 4096*4096*2 = 32 MB

    prep_input_k<<<(TOK * DIM_IN) / (256 * 8), 256, 0, stream>>>(input, Abf);
    prep_weight_k<<<(DIM_OUT / 128) * (DIM_IN / 128), 256, 0, stream>>>(wq, scale, U, s, V, Wbf);
    gemm_k<<<(TOK / 256) * (DIM_OUT / 256), 512, 0, stream>>>(Abf, Wbf, bias, out);
}

// Round 4
// 329.940 us; speedup vs baseline: 1.5066x; 1.0263x over previous
//
#include <hip/hip_runtime.h>
#include <stdint.h>

typedef unsigned short ushort_t;
typedef __attribute__((ext_vector_type(8))) short short8;
typedef __attribute__((ext_vector_type(8))) unsigned short ushort8;
typedef __attribute__((ext_vector_type(4))) float f32x4;

#define TOK 8192
#define DIM_IN 4096
#define DIM_OUT 4096
#define RANK 64
#define NT (DIM_IN / 64)   // 64 K-tiles of BK=64

// fp32 -> bf16 round-to-nearest-even
__device__ __forceinline__ ushort_t f2bf(float f) {
    unsigned u = __float_as_uint(f);
    unsigned r = (u + 0x7fffu + ((u >> 16) & 1u)) >> 16;
    return (ushort_t)r;
}

__device__ __forceinline__ void gload16(const void* g, void* l) {
    __builtin_amdgcn_global_load_lds(
        (const __attribute__((address_space(1))) unsigned int*)g,
        (__attribute__((address_space(3))) unsigned int*)l,
        16, 0, 0);
}

// ---------------- Kernel 1: input fp32 -> bf16 ----------------
__global__ __launch_bounds__(256) void prep_input_k(const float* __restrict__ in,
                                                    ushort_t* __restrict__ out) {
    size_t idx = (size_t)blockIdx.x * 256 + threadIdx.x;
    const float4* p = (const float4*)(in + idx * 8);
    float4 f0 = p[0], f1 = p[1];
    ushort8 o;
    o[0] = f2bf(f0.x); o[1] = f2bf(f0.y); o[2] = f2bf(f0.z); o[3] = f2bf(f0.w);
    o[4] = f2bf(f1.x); o[5] = f2bf(f1.y); o[6] = f2bf(f1.z); o[7] = f2bf(f1.w);
    *(ushort8*)(out + idx * 8) = o;
}

// ---------------- Kernel 2: W_eff = dequant(Wq,scale) + U*diag(s)*V^T -> bf16 ----------------
__global__ __launch_bounds__(256) void prep_weight_k(const float* __restrict__ wq,
                                                     const float* __restrict__ scale,
                                                     const float* __restrict__ U,
                                                     const float* __restrict__ s,
                                                     const float* __restrict__ V,
                                                     ushort_t* __restrict__ Wb) {
    __shared__ float Us[128][64];
    __shared__ float Vs[128][64];
    int tid = threadIdx.x;
    int ob = blockIdx.x >> 5;
    int kb = blockIdx.x & 31;

#pragma unroll
    for (int j = 0; j < 8; ++j) {
        int c = j * 256 + tid;
        int row = c >> 4;
        int col = (c & 15) * 4;
        float4 u = *(const float4*)&U[(size_t)(ob * 128 + row) * RANK + col];
        float4 sv = *(const float4*)&s[col];
        u.x *= sv.x; u.y *= sv.y; u.z *= sv.z; u.w *= sv.w;
        *(float4*)&Us[row][col] = u;
        float4 v = *(const float4*)&V[(size_t)(kb * 128 + row) * RANK + col];
        *(float4*)&Vs[row][col] = v;
    }
    __syncthreads();

    int ty = tid >> 4, tx = tid & 15;
    float acc[8][8];
#pragma unroll
    for (int i = 0; i < 8; ++i)
#pragma unroll
        for (int j = 0; j < 8; ++j) acc[i][j] = 0.f;

#pragma unroll 4
    for (int r4 = 0; r4 < 16; ++r4) {
        float4 u[8], v[8];
#pragma unroll
        for (int i = 0; i < 8; ++i) u[i] = *(const float4*)&Us[ty * 8 + i][r4 * 4];
#pragma unroll
        for (int j = 0; j < 8; ++j) v[j] = *(const float4*)&Vs[tx * 8 + j][r4 * 4];
#pragma unroll
        for (int i = 0; i < 8; ++i)
#pragma unroll
            for (int j = 0; j < 8; ++j)
                acc[i][j] += u[i].x * v[j].x + u[i].y * v[j].y + u[i].z * v[j].z + u[i].w * v[j].w;
    }

#pragma unroll
    for (int i = 0; i < 8; ++i) {
        int o = ob * 128 + ty * 8 + i;
        int k0 = kb * 128 + tx * 8;
        float sc = scale[(size_t)o * (DIM_IN / 32) + (k0 >> 5)];
        float4 q0 = *(const float4*)&wq[(size_t)o * DIM_IN + k0];
        float4 q1 = *(const float4*)&wq[(size_t)o * DIM_IN + k0 + 4];
        ushort8 w;
        w[0] = f2bf(q0.x * sc + acc[i][0]);
        w[1] = f2bf(q0.y * sc + acc[i][1]);
        w[2] = f2bf(q0.z * sc + acc[i][2]);
        w[3] = f2bf(q0.w * sc + acc[i][3]);
        w[4] = f2bf(q1.x * sc + acc[i][4]);
        w[5] = f2bf(q1.y * sc + acc[i][5]);
        w[6] = f2bf(q1.z * sc + acc[i][6]);
        w[7] = f2bf(q1.w * sc + acc[i][7]);
        *(ushort8*)&Wb[(size_t)o * DIM_IN + k0] = w;
    }
}

// ---------------- Kernel 3: 256^2 GEMM, C = A @ B^T + bias ----------------
// 512 threads (8 waves, 2M x 4N), BK=64, st_16x32-swizzled LDS, counted vmcnt(6).
// Tile = 8 segments of 8 MFMA (quadrant x kk-half); each segment's ds_reads are
// issued one segment AHEAD, so LDS read service hides under the previous MFMA
// cluster. Phase order (m03n01)(m03n23)(m47n23)(m47n01) lets operand register
// half-sets ping-pong: aA/aB (a03 -> a47), bA = b01 (tile-lifetime), bB = b23.
// Barriers: only P1-end (B reads drained), P2-end (A reads drained), tile-end
// (+vmcnt). Stage slots/accounting identical to the proven r2 schedule.
__global__ __launch_bounds__(512, 2) void gemm_k(const ushort_t* __restrict__ A,
                                                 const ushort_t* __restrict__ B,
                                                 const float* __restrict__ bias,
                                                 float* __restrict__ C) {
    __shared__ ushort_t lds[2][2][2][8192];

    const int tid = threadIdx.x;
    const int wid = tid >> 6;
    const int lane = tid & 63;

    // XCD-aware bijective swizzle: 512 blocks, 8 XCDs, 64 per XCD
    int bid = blockIdx.x;
    int swz = (bid & 7) * 64 + (bid >> 3);
    const int bm = swz >> 4;   // 32 M-tiles
    const int bn = swz & 15;   // 16 N-tiles

    const int wr = wid >> 2;   // 0..1 (M)
    const int wc = wid & 3;    // 0..3 (N)

    // --- staging: wave wid fills subtiles {wid, wid+8} of each 128x64 half-tile.
    const int lane2 = lane ^ (((lane >> 5) & 1) << 1);
    const int srow = (wid >> 1) * 16 + (lane2 >> 2);
    const int scol = (wid & 1) * 32 + (lane2 & 3) * 8;
    const ushort_t* pa = A + (size_t)(bm * 256 + srow) * DIM_IN + scol;
    const ushort_t* pb = B + (size_t)(bn * 256 + srow) * DIM_IN + scol;

    // --- swizzled per-lane ds_read offset (element units)
    const int loff = ((((lane & 15) * 64 + (lane >> 4) * 16) ^ (((lane >> 3) & 1) << 5)) >> 1);

    f32x4 acc[8][4] = {};

    auto stageA = [&](int buf, int half, int t) {
        const ushort_t* g = pa + (size_t)half * 128 * DIM_IN + t * 64;
        gload16(g, &lds[buf][0][half][wid * 512]);
        gload16(g + (size_t)64 * DIM_IN, &lds[buf][0][half][(wid + 8) * 512]);
    };
    auto stageB = [&](int buf, int half, int t) {
        const ushort_t* g = pb + (size_t)half * 128 * DIM_IN + t * 64;
        gload16(g, &lds[buf][1][half][wid * 512]);
        gload16(g + (size_t)64 * DIM_IN, &lds[buf][1][half][(wid + 8) * 512]);
    };

    // mode: 2 = steady state; 1 = t=NT-2 (only P0 stage, vmcnt(0)); 0 = last tile
    auto tile_step = [&](int buf, int t, int mode) {
        const ushort_t* LA = &lds[buf][0][wr][0];
        const ushort_t* LB = &lds[buf][1][wc >> 1][0];
        const int bsub = (wc & 1) * 4;
        short8 aA[4], aB[4], bA[2][2], bB[2][2];

        auto rdA = [&](short8 (&dst)[4], int mhalf, int kk) {
#pragma unroll
            for (int m = 0; m < 4; ++m)
                dst[m] = *(const short8*)(LA + ((((mhalf * 4 + m) * 2) + kk) << 9) + loff);
        };
        auto rdB = [&](short8 (&dst)[2][2], int noff, int kk) {
#pragma unroll
            for (int n = 0; n < 2; ++n)
                dst[n][kk] = *(const short8*)(LB + ((((bsub + noff + n) * 2) + kk) << 9) + loff);
        };
        auto cluster = [&](short8 (&av)[4], short8 (&bv)[2][2], int kk, int mb, int nb) {
            __builtin_amdgcn_s_setprio(1);
#pragma unroll
            for (int m = 0; m < 4; ++m)
#pragma unroll
                for (int n = 0; n < 2; ++n)
                    acc[mb + m][nb + n] =
                        __builtin_amdgcn_mfma_f32_16x16x32_bf16(av[m], bv[n][kk], acc[mb + m][nb + n], 0, 0, 0);
            __builtin_amdgcn_s_setprio(0);
        };

        // ---- PH0 (m0-3 x n0-1): seg0+seg1 reads up front (tile-boundary exposure)
        rdA(aA, 0, 0);                 // seg0: a03 k0  [4]
        rdB(bA, 0, 0);                 // seg0: b01 k0  [2]
        rdA(aB, 0, 1);                 // seg1: a03 k1  [4]
        rdB(bA, 0, 1);                 // seg1: b01 k1  [2]
        if (mode >= 1) stageA(buf ^ 1, 1, t + 1);
        cluster(aA, bA, 0, 0, 0);      // seg0
        rdB(bB, 2, 0);                 // seg2 ops: b23 k0 [2]
        cluster(aB, bA, 1, 0, 0);      // seg1

        // ---- PH1 (m0-3 x n2-3)
        rdB(bB, 2, 1);                 // seg3 ops: b23 k1 [2]
        cluster(aA, bB, 0, 0, 2);      // seg2 (last use of a03 k0)
        rdA(aA, 1, 0);                 // seg4 ops: a47 k0 -> reuse aA (WAR after seg2)
        cluster(aB, bB, 1, 0, 2);      // seg3 (last use of a03 k1)
        __builtin_amdgcn_s_barrier();  // P1-end: all waves' B(t) reads complete

        // ---- PH2 (m4-7 x n2-3): B region of buf now safe to restage
        rdA(aB, 1, 1);                 // seg5 ops: a47 k1 -> reuse aB
        if (mode == 2) { stageB(buf, 0, t + 2); stageB(buf, 1, t + 2); }
        cluster(aA, bB, 0, 4, 2);      // seg4
        cluster(aB, bB, 1, 4, 2);      // seg5 (last use of b23)
        __builtin_amdgcn_s_barrier();  // P2-end: all waves' A(t) reads complete

        // ---- PH3 (m4-7 x n0-1): no reads; A region safe to restage
        if (mode == 2) stageA(buf, 0, t + 2);
        cluster(aA, bA, 0, 4, 0);      // seg6
        cluster(aB, bA, 1, 4, 0);      // seg7
        if (mode == 2)
            asm volatile("s_waitcnt vmcnt(6)" ::: "memory");   // tile t+1 fully landed
        else if (mode == 1)
            asm volatile("s_waitcnt vmcnt(0)" ::: "memory");   // tail drain
        if (mode >= 1) __builtin_amdgcn_s_barrier();           // tile-end
    };

    // ---- prologue: tile0 (4 halves) + tile1 (B0,B1,A0); A1(t1) staged at t0.P0
    stageA(0, 0, 0); stageA(0, 1, 0); stageB(0, 0, 0); stageB(0, 1, 0);
    stageB(1, 0, 1); stageB(1, 1, 1); stageA(1, 0, 1);
    asm volatile("s_waitcnt vmcnt(6)" ::: "memory");           // tile0 landed
    __builtin_amdgcn_s_barrier();

    for (int t = 0; t < NT - 2; t += 2) {
        tile_step(0, t, 2);
        tile_step(1, t + 1, 2);
    }
    tile_step(0, NT - 2, 1);
    tile_step(1, NT - 1, 0);

    // ---- epilogue: C/D layout col = lane&15, row = (lane>>4)*4 + reg
    const int ccol = lane & 15;
    const int crow = (lane >> 4) * 4;
#pragma unroll
    for (int n = 0; n < 4; ++n) {
        int gcol = bn * 256 + wc * 64 + n * 16 + ccol;
        float bv = bias[gcol];
#pragma unroll
        for (int m = 0; m < 8; ++m) {
            size_t grow = (size_t)(bm * 256 + wr * 128 + m * 16 + crow);
#pragma unroll
            for (int r = 0; r < 4; ++r)
                C[(grow + r) * DIM_OUT + gcol] = acc[m][n][r] + bv;
        }
    }
}

extern "C" void kernel_launch(void* const* d_in, const int* in_sizes, int n_in,
                              void* d_out, int out_size, void* d_ws, size_t ws_size,
                              hipStream_t stream) {
    const float* input = (const float*)d_in[0];
    const float* wq    = (const float*)d_in[1];
    const float* scale = (const float*)d_in[2];
    const float* bias  = (const float*)d_in[3];
    const float* U     = (const float*)d_in[4];
    const float* s     = (const float*)d_in[5];
    const float* V     = (const float*)d_in[6];
    float* out = (float*)d_out;

    ushort_t* Abf = (ushort_t*)d_ws;                       // 8192*4096*2 = 64 MB
    ushort_t* Wbf = Abf + (size_t)TOK * DIM_IN;            // 4096*4096*2 = 32 MB

    prep_input_k<<<(TOK * DIM_IN) / (256 * 8), 256, 0, stream>>>(input, Abf);
    prep_weight_k<<<(DIM_OUT / 128) * (DIM_IN / 128), 256, 0, stream>>>(wq, scale, U, s, V, Wbf);
    gemm_k<<<(TOK / 256) * (DIM_OUT / 256), 512, 0, stream>>>(Abf, Wbf, bias, out);
}